// Round 3
// baseline (467.869 us; speedup 1.0000x reference)
//
#include <hip/hip_runtime.h>
#include <hip/hip_bf16.h>

#define NSITES 100000
#define KOFFS 27
#define CIN 64
#define COUT 128

typedef unsigned short u16;
typedef __attribute__((ext_vector_type(8))) short s16x8;
typedef __attribute__((ext_vector_type(4))) float f32x4;

static __device__ __forceinline__ u16 f2bf(float f) {
    union { float f; unsigned u; } x; x.f = f;
    return (u16)((x.u + 0x7FFFu + ((x.u >> 16) & 1u)) >> 16);
}
static __device__ __forceinline__ float bf2f(u16 v) {
    union { unsigned u; float f; } x; x.u = ((unsigned)v) << 16;
    return x.f;
}

// ---------- prep: transpose/convert weights to bf16 [k][d][c], zero stat partials ----------
__global__ void prep_kernel(const float* __restrict__ W1, const float* __restrict__ W2,
                            const float* __restrict__ Wsk,
                            u16* __restrict__ W1t, u16* __restrict__ W2t,
                            u16* __restrict__ Wskt, float* __restrict__ zero_area) {
    int i = blockIdx.x * 256 + threadIdx.x;
    if (i < 27 * 64 * 128) {
        int k = i / 8192, r = i & 8191, d = r >> 6, c = r & 63;
        W1t[i] = f2bf(W1[k * 8192 + c * 128 + d]);
        return;
    }
    i -= 27 * 64 * 128;
    if (i < 27 * 128 * 128) {
        int k = i / 16384, r = i & 16383, d = r >> 7, c = r & 127;
        W2t[i] = f2bf(W2[k * 16384 + c * 128 + d]);
        return;
    }
    i -= 27 * 128 * 128;
    if (i < 8192) {
        int d = i >> 6, c = i & 63;
        Wskt[i] = f2bf(Wsk[c * 128 + d]);
        return;
    }
    i -= 8192;
    zero_area[i] = 0.0f;  // 4 * 64*128 partial-stat floats
}

// ---------- x (fp32) -> bf16 rows, plus zero sentinel row N ----------
__global__ void convert_x_kernel(const float* __restrict__ x, u16* __restrict__ xb) {
    long long e = ((long long)blockIdx.x * 256 + threadIdx.x) * 8;
    if (e >= (long long)(NSITES + 1) * CIN) return;
    s16x8 o;
    if (e < (long long)NSITES * CIN) {
        float4 v0 = *(const float4*)(x + e);
        float4 v1 = *(const float4*)(x + e + 4);
        o[0] = (short)f2bf(v0.x); o[1] = (short)f2bf(v0.y);
        o[2] = (short)f2bf(v0.z); o[3] = (short)f2bf(v0.w);
        o[4] = (short)f2bf(v1.x); o[5] = (short)f2bf(v1.y);
        o[6] = (short)f2bf(v1.z); o[7] = (short)f2bf(v1.w);
    } else {
#pragma unroll
        for (int j = 0; j < 8; ++j) o[j] = 0;
    }
    *(s16x8*)(xb + e) = o;
}

// ---------- gather-GEMM conv: double-buffered LDS, ONE barrier per stage ----------
// y[n0+r, :] = sum_k xin[nbr[r,k]] @ Wt[k]^T ; Wt layout [nk][COUT][CK] bf16.
// Block: 256 thr = 4 waves, 64-row tile; wave w owns output cols [32w, 32w+32).
// Stage k: issue gathers(k+1)->regs + B(k)->regs, MFMA(k) from buf[k&1],
// ds_write regs->buf[(k+1)&1] (vmcnt wait lands AFTER the MFMA phase), one barrier.
// Rationale: compiler drains vmcnt(0) at every s_barrier, so loads only survive
// within a stage -- give them the whole MFMA phase to land.
template <int CK, bool IDENT_FUSE, bool STATS>
__global__ __launch_bounds__(256, (CK == 64 ? 4 : 3)) void conv_kernel(
    const u16* __restrict__ xin, const int* __restrict__ nbr,
    const u16* __restrict__ Wt, u16* __restrict__ yout,
    float* __restrict__ psum, float* __restrict__ psq, int nk,
    const u16* __restrict__ Wskt, float* __restrict__ outid) {
    constexpr int STRIDE = CK + 8;   // +8 bf16 pad -> 2-way bank aliasing (free, m136)
    constexpr int KSTEPS = CK / 32;
    constexpr int CPR = CK / 8;      // 16B chunks per row
    constexpr int RPP = 256 / CPR;   // rows staged per pass
    constexpr int NPASS = 64 / RPP;
    __shared__ __align__(16) u16 a_tile[2][64 * STRIDE];
    __shared__ int nbr_tile[64 * KOFFS];

    const int tid = threadIdx.x;
    const int wave = tid >> 6;
    const int lane = tid & 63;
    const int m = lane & 15;
    const int q = lane >> 4;
    const int n0 = blockIdx.x * 64;
    const int wc = wave * 32;
    const int srow = tid / CPR;
    const int schunk = tid % CPR;

    for (int i = tid; i < 64 * KOFFS; i += 256) {
        int r = i / KOFFS;
        int kk = i - r * KOFFS;
        int row = n0 + r;
        nbr_tile[i] = (row < NSITES) ? nbr[row * KOFFS + kk] : NSITES;
    }
    __syncthreads();

    f32x4 acc[4][2];
#pragma unroll
    for (int rt = 0; rt < 4; ++rt)
#pragma unroll
        for (int ct = 0; ct < 2; ++ct)
#pragma unroll
            for (int r = 0; r < 4; ++r) acc[rt][ct][r] = 0.0f;

    // prologue: gather k=0, stage into buf0
    s16x8 ag[NPASS];
#pragma unroll
    for (int p = 0; p < NPASS; ++p) {
        int r = p * RPP + srow;
        ag[p] = *(const s16x8*)(xin + (long long)nbr_tile[r * KOFFS] * CK + schunk * 8);
    }
#pragma unroll
    for (int p = 0; p < NPASS; ++p)
        *(s16x8*)(a_tile[0] + (p * RPP + srow) * STRIDE + schunk * 8) = ag[p];
    __syncthreads();

    for (int k = 0; k < nk; ++k) {
        const u16* abuf = a_tile[k & 1];
        u16* wbuf = a_tile[(k + 1) & 1];
        const bool more = (k + 1 < nk);

        // issue gathers for k+1 (land during this stage's MFMA phase)
        if (more) {
#pragma unroll
            for (int p = 0; p < NPASS; ++p) {
                int r = p * RPP + srow;
                ag[p] = *(const s16x8*)(xin + (long long)nbr_tile[r * KOFFS + k + 1] * CK + schunk * 8);
            }
        }

        // B fragments for this k (L2-hot: all blocks read the same 32KB)
        s16x8 bf[2][KSTEPS];
        const u16* wb = Wt + (long long)k * (COUT * CK);
#pragma unroll
        for (int ct = 0; ct < 2; ++ct)
#pragma unroll
            for (int ks = 0; ks < KSTEPS; ++ks)
                bf[ct][ks] = *(const s16x8*)(wb + (wc + ct * 16 + m) * CK + ks * 32 + q * 8);

        // MFMA phase on current buffer
#pragma unroll
        for (int ks = 0; ks < KSTEPS; ++ks) {
            s16x8 af[4];
#pragma unroll
            for (int rt = 0; rt < 4; ++rt)
                af[rt] = *(const s16x8*)(abuf + (rt * 16 + m) * STRIDE + ks * 32 + q * 8);
#pragma unroll
            for (int rt = 0; rt < 4; ++rt)
#pragma unroll
                for (int ct = 0; ct < 2; ++ct)
                    acc[rt][ct] = __builtin_amdgcn_mfma_f32_16x16x32_bf16(
                        af[rt], bf[ct][ks], acc[rt][ct], 0, 0, 0);
        }

        // stage k+1 into the other buffer (vmcnt wait for ag happens here, post-MFMA)
        if (more) {
#pragma unroll
            for (int p = 0; p < NPASS; ++p)
                *(s16x8*)(wbuf + (p * RPP + srow) * STRIDE + schunk * 8) = ag[p];
        }
        __syncthreads();  // writes visible for k+1; reads of abuf done before k+2 overwrites
    }

    // Store y (bf16): C/D layout col=lane&15, row=(lane>>4)*4+reg  [m89-verified]
#pragma unroll
    for (int rt = 0; rt < 4; ++rt) {
        int rowb = n0 + rt * 16 + q * 4;
#pragma unroll
        for (int ct = 0; ct < 2; ++ct) {
            int col = wc + ct * 16 + m;
#pragma unroll
            for (int r = 0; r < 4; ++r) {
                int row = rowb + r;
                if (row < NSITES) yout[(long long)row * COUT + col] = f2bf(acc[rt][ct][r]);
            }
        }
    }

    if (STATS) {
#pragma unroll
        for (int ct = 0; ct < 2; ++ct) {
            float s = 0.f, ss = 0.f;
#pragma unroll
            for (int rt = 0; rt < 4; ++rt)
#pragma unroll
                for (int r = 0; r < 4; ++r) {
                    float v = acc[rt][ct][r];
                    s += v; ss += v * v;
                }
            s += __shfl_xor(s, 16); ss += __shfl_xor(ss, 16);
            s += __shfl_xor(s, 32); ss += __shfl_xor(ss, 32);
            if (q == 0) {
                int col = wc + ct * 16 + m;
                int slot = blockIdx.x & 63;  // 64-slot tree cuts atomic contention
                atomicAdd(psum + slot * COUT + col, s);
                atomicAdd(psq + slot * COUT + col, ss);
            }
        }
    }

    if (IDENT_FUSE) {
        // identity = x @ W_skip for the same 64 rows (no gather); reuses acc regs
#pragma unroll
        for (int rt = 0; rt < 4; ++rt)
#pragma unroll
            for (int ct = 0; ct < 2; ++ct)
#pragma unroll
                for (int r = 0; r < 4; ++r) acc[rt][ct][r] = 0.0f;
        s16x8 aid[NPASS];
#pragma unroll
        for (int p = 0; p < NPASS; ++p) {
            int row = n0 + p * RPP + srow;
            long long idx = (row < NSITES) ? row : NSITES;
            aid[p] = *(const s16x8*)(xin + idx * CK + schunk * 8);
        }
        s16x8 bfi[2][KSTEPS];
#pragma unroll
        for (int ct = 0; ct < 2; ++ct)
#pragma unroll
            for (int ks = 0; ks < KSTEPS; ++ks)
                bfi[ct][ks] = *(const s16x8*)(Wskt + (wc + ct * 16 + m) * CK + ks * 32 + q * 8);
        // final barrier of main loop guarantees a_tile[0] reads are complete
#pragma unroll
        for (int p = 0; p < NPASS; ++p)
            *(s16x8*)(a_tile[0] + (p * RPP + srow) * STRIDE + schunk * 8) = aid[p];
        __syncthreads();
#pragma unroll
        for (int ks = 0; ks < KSTEPS; ++ks) {
            s16x8 af[4];
#pragma unroll
            for (int rt = 0; rt < 4; ++rt)
                af[rt] = *(const s16x8*)(a_tile[0] + (rt * 16 + m) * STRIDE + ks * 32 + q * 8);
#pragma unroll
            for (int rt = 0; rt < 4; ++rt)
#pragma unroll
                for (int ct = 0; ct < 2; ++ct)
                    acc[rt][ct] = __builtin_amdgcn_mfma_f32_16x16x32_bf16(
                        af[rt], bfi[ct][ks], acc[rt][ct], 0, 0, 0);
        }
#pragma unroll
        for (int rt = 0; rt < 4; ++rt) {
            int rowb = n0 + rt * 16 + q * 4;
#pragma unroll
            for (int ct = 0; ct < 2; ++ct) {
                int col = wc + ct * 16 + m;
#pragma unroll
                for (int r = 0; r < 4; ++r) {
                    int row = rowb + r;
                    if (row < NSITES) outid[(long long)row * COUT + col] = acc[rt][ct][r];
                }
            }
        }
    }
}

// ---------- reduce 64 slots -> per-column affine (a = gamma*rsqrt(var+eps), b = beta - mu*a) ----------
__global__ void bn_stats_kernel(const float* __restrict__ psum, const float* __restrict__ psq,
                                const float* __restrict__ gamma, const float* __restrict__ beta,
                                float* __restrict__ ab) {
    int col = threadIdx.x;  // 128 threads
    float s = 0.f, ss = 0.f;
    for (int i = 0; i < 64; ++i) { s += psum[i * COUT + col]; ss += psq[i * COUT + col]; }
    const float inv_n = 1.0f / (float)NSITES;
    float mu = s * inv_n;
    float var = ss * inv_n - mu * mu;
    float rs = rsqrtf(var + 1e-5f);
    float a = gamma[col] * rs;
    ab[col] = a;
    ab[COUT + col] = beta[col] - mu * a;
}

// ---------- h = bf16(relu(y*a+b)), plus zero sentinel row; y is bf16 ----------
__global__ void bn_apply_kernel(const u16* __restrict__ y, const float* __restrict__ ab,
                                u16* __restrict__ h) {
    long long e = ((long long)blockIdx.x * 256 + threadIdx.x) * 8;
    if (e >= (long long)(NSITES + 1) * COUT) return;
    s16x8 o;
    if (e < (long long)NSITES * COUT) {
        int cb = (int)(e & (COUT - 1));
        s16x8 v = *(const s16x8*)(y + e);
#pragma unroll
        for (int j = 0; j < 8; ++j) {
            float r = bf2f((u16)v[j]) * ab[cb + j] + ab[COUT + cb + j];
            o[j] = (short)f2bf(fmaxf(r, 0.f));
        }
    } else {
#pragma unroll
        for (int j = 0; j < 8; ++j) o[j] = 0;
    }
    *(s16x8*)(h + e) = o;
}

// ---------- out = relu(y*a+b) + identity (identity resident in d_out); y is bf16 ----------
__global__ void final_kernel(const u16* __restrict__ y, const float* __restrict__ ab,
                             float* __restrict__ out) {
    long long e = ((long long)blockIdx.x * 256 + threadIdx.x) * 8;
    if (e >= (long long)NSITES * COUT) return;
    int cb = (int)(e & (COUT - 1));
    s16x8 v = *(const s16x8*)(y + e);
    float4 i0 = *(const float4*)(out + e);
    float4 i1 = *(const float4*)(out + e + 4);
    float is[8] = {i0.x, i0.y, i0.z, i0.w, i1.x, i1.y, i1.z, i1.w};
    float os[8];
#pragma unroll
    for (int j = 0; j < 8; ++j) {
        float r = bf2f((u16)v[j]) * ab[cb + j] + ab[COUT + cb + j];
        os[j] = fmaxf(r, 0.f) + is[j];
    }
    *(float4*)(out + e) = make_float4(os[0], os[1], os[2], os[3]);
    *(float4*)(out + e + 4) = make_float4(os[4], os[5], os[6], os[7]);
}

extern "C" void kernel_launch(void* const* d_in, const int* in_sizes, int n_in,
                              void* d_out, int out_size, void* d_ws, size_t ws_size,
                              hipStream_t stream) {
    const float* x   = (const float*)d_in[0];
    const int*   nbr = (const int*)d_in[1];
    const float* W1  = (const float*)d_in[2];
    const float* g1  = (const float*)d_in[3];
    const float* b1  = (const float*)d_in[4];
    const float* W2  = (const float*)d_in[5];
    const float* g2  = (const float*)d_in[6];
    const float* b2  = (const float*)d_in[7];
    const float* Wsk = (const float*)d_in[8];
    float* out = (float*)d_out;

    // workspace layout (bytes, 16B-aligned); total ~66 MB
    char* ws = (char*)d_ws;
    u16*   xb   = (u16*)(ws);                    // (N+1)*64 bf16      = 12,800,128 B
    u16*   W1t  = (u16*)(ws + 12800128);         // 27*128*64 bf16     =    442,368 B
    u16*   W2t  = (u16*)(ws + 13242496);         // 27*128*128 bf16    =    884,736 B
    u16*   Wskt = (u16*)(ws + 14127232);         // 128*64 bf16        =     16,384 B
    u16*   y    = (u16*)(ws + 14143616);         // N*128 bf16         = 25,600,000 B
    u16*   h1   = (u16*)(ws + 39743616);         // (N+1)*128 bf16     = 25,600,256 B
    float* ps1  = (float*)(ws + 65343872);       // 4 * 64*128 f32 partials
    float* pq1  = ps1 + 8192;
    float* ps2  = pq1 + 8192;
    float* pq2  = ps2 + 8192;
    float* ab1  = pq2 + 8192;                    // 2*2*128 f32 affine params
    float* ab2  = ab1 + 256;

    const int NBLK = (NSITES + 63) / 64;  // 1563

    prep_kernel<<<2752, 256, 0, stream>>>(W1, W2, Wsk, W1t, W2t, Wskt, ps1);
    convert_x_kernel<<<3126, 256, 0, stream>>>(x, xb);
    // conv1 + fused stats + fused identity (identity -> d_out)
    conv_kernel<64, true, true><<<NBLK, 256, 0, stream>>>(xb, nbr, W1t, y, ps1, pq1, KOFFS, Wskt, out);
    bn_stats_kernel<<<1, 128, 0, stream>>>(ps1, pq1, g1, b1, ab1);
    bn_apply_kernel<<<6251, 256, 0, stream>>>(y, ab1, h1);
    // conv2 + fused stats (reuses y buffer)
    conv_kernel<128, false, true><<<NBLK, 256, 0, stream>>>(h1, nbr, W2t, y, ps2, pq2, KOFFS, nullptr, nullptr);
    bn_stats_kernel<<<1, 128, 0, stream>>>(ps2, pq2, g2, b2, ab2);
    final_kernel<<<6250, 256, 0, stream>>>(y, ab2, out);
}

// Round 4
// 467.163 us; speedup vs baseline: 1.0015x; 1.0015x over previous
//
#include <hip/hip_runtime.h>
#include <hip/hip_bf16.h>

#define NSITES 100000
#define KOFFS 27
#define CIN 64
#define COUT 128

typedef unsigned short u16;
typedef __attribute__((ext_vector_type(8))) short s16x8;
typedef __attribute__((ext_vector_type(4))) float f32x4;

static __device__ __forceinline__ u16 f2bf(float f) {
    union { float f; unsigned u; } x; x.f = f;
    return (u16)((x.u + 0x7FFFu + ((x.u >> 16) & 1u)) >> 16);
}
static __device__ __forceinline__ float bf2f(u16 v) {
    union { unsigned u; float f; } x; x.u = ((unsigned)v) << 16;
    return x.f;
}

// ---------- prep: transpose/convert weights to bf16 [k][d][c], zero stat partials ----------
__global__ void prep_kernel(const float* __restrict__ W1, const float* __restrict__ W2,
                            const float* __restrict__ Wsk,
                            u16* __restrict__ W1t, u16* __restrict__ W2t,
                            u16* __restrict__ Wskt, float* __restrict__ zero_area) {
    int i = blockIdx.x * 256 + threadIdx.x;
    if (i < 27 * 64 * 128) {
        int k = i / 8192, r = i & 8191, d = r >> 6, c = r & 63;
        W1t[i] = f2bf(W1[k * 8192 + c * 128 + d]);
        return;
    }
    i -= 27 * 64 * 128;
    if (i < 27 * 128 * 128) {
        int k = i / 16384, r = i & 16383, d = r >> 7, c = r & 127;
        W2t[i] = f2bf(W2[k * 16384 + c * 128 + d]);
        return;
    }
    i -= 27 * 128 * 128;
    if (i < 8192) {
        int d = i >> 6, c = i & 63;
        Wskt[i] = f2bf(Wsk[c * 128 + d]);
        return;
    }
    i -= 8192;
    zero_area[i] = 0.0f;  // 4 * 64*128 partial-stat floats
}

// ---------- x (fp32) -> bf16 rows, plus zero sentinel row N ----------
__global__ void convert_x_kernel(const float* __restrict__ x, u16* __restrict__ xb) {
    long long e = ((long long)blockIdx.x * 256 + threadIdx.x) * 8;
    if (e >= (long long)(NSITES + 1) * CIN) return;
    s16x8 o;
    if (e < (long long)NSITES * CIN) {
        float4 v0 = *(const float4*)(x + e);
        float4 v1 = *(const float4*)(x + e + 4);
        o[0] = (short)f2bf(v0.x); o[1] = (short)f2bf(v0.y);
        o[2] = (short)f2bf(v0.z); o[3] = (short)f2bf(v0.w);
        o[4] = (short)f2bf(v1.x); o[5] = (short)f2bf(v1.y);
        o[6] = (short)f2bf(v1.z); o[7] = (short)f2bf(v1.w);
    } else {
#pragma unroll
        for (int j = 0; j < 8; ++j) o[j] = 0;
    }
    *(s16x8*)(xb + e) = o;
}

// ---------- gather-GEMM conv: double-buffered LDS, one barrier/stage ----------
// y[n0+r, :] = sum_k xin[nbr[r,k]] @ Wt[k]^T ; Wt layout [nk][COUT][CK] bf16.
// Block: 256 thr = 4 waves, 64-row tile; wave w owns output cols [32w, 32w+32).
// VMEM ISSUE ORDER IS THE POINT: B(k) first (oldest -> MFMA's vmcnt wait covers
// only these), then gathers(k+1) (in flight through the MFMA phase), then
// nbr-idx(k+2) (kept in regs so gather issue never stalls on an index load).
// A-tile is XOR-swizzled (chunk ^= row&(CPR-1)): 2-way banks (free), no pad,
// LDS = 2*64*CK*2 B only -> 4 blocks/CU at CK=128.
template <int CK, bool IDENT_FUSE, bool STATS>
__global__ __launch_bounds__(256, 4) void conv_kernel(
    const u16* __restrict__ xin, const int* __restrict__ nbr,
    const u16* __restrict__ Wt, u16* __restrict__ yout,
    float* __restrict__ psum, float* __restrict__ psq, int nk,
    const u16* __restrict__ Wskt, float* __restrict__ outid) {
    constexpr int KSTEPS = CK / 32;
    constexpr int CPR = CK / 8;      // 16B chunks per row
    constexpr int SWZ = CPR - 1;
    constexpr int RPP = 256 / CPR;   // rows staged per pass
    constexpr int NPASS = 64 / RPP;
    __shared__ __align__(16) u16 a_tile[2][64 * CK];

    const int tid = threadIdx.x;
    const int wave = tid >> 6;
    const int lane = tid & 63;
    const int m = lane & 15;
    const int q = lane >> 4;
    const int n0 = blockIdx.x * 64;
    const int wc = wave * 32;
    const int srow = tid / CPR;
    const int schunk = tid % CPR;

    f32x4 acc[4][2];
#pragma unroll
    for (int rt = 0; rt < 4; ++rt)
#pragma unroll
        for (int ct = 0; ct < 2; ++ct)
#pragma unroll
            for (int r = 0; r < 4; ++r) acc[rt][ct][r] = 0.0f;

    // prologue: gather k=0 -> buf0; preload idx for k=1
    int nidx[NPASS];
    s16x8 ag[NPASS];
#pragma unroll
    for (int p = 0; p < NPASS; ++p) {
        int row = n0 + p * RPP + srow;
        nidx[p] = (row < NSITES) ? nbr[row * KOFFS] : NSITES;
    }
#pragma unroll
    for (int p = 0; p < NPASS; ++p)
        ag[p] = *(const s16x8*)(xin + (long long)nidx[p] * CK + schunk * 8);
#pragma unroll
    for (int p = 0; p < NPASS; ++p) {
        int row = n0 + p * RPP + srow;
        nidx[p] = (row < NSITES && nk > 1) ? nbr[row * KOFFS + 1] : NSITES;
    }
#pragma unroll
    for (int p = 0; p < NPASS; ++p) {
        int r = p * RPP + srow;
        *(s16x8*)(a_tile[0] + r * CK + ((schunk ^ (r & SWZ)) * 8)) = ag[p];
    }
    __syncthreads();

    for (int k = 0; k < nk; ++k) {
        const u16* abuf = a_tile[k & 1];
        u16* wbuf = a_tile[(k + 1) & 1];
        const bool more = (k + 1 < nk);

        // 1. B fragments FIRST (oldest in vm queue; L2-hot: all blocks share 32KB)
        s16x8 bf[2][KSTEPS];
        const u16* wb = Wt + (long long)k * (COUT * CK);
#pragma unroll
        for (int ct = 0; ct < 2; ++ct)
#pragma unroll
            for (int ks = 0; ks < KSTEPS; ++ks)
                bf[ct][ks] = *(const s16x8*)(wb + (wc + ct * 16 + m) * CK + ks * 32 + q * 8);

        // 2. gathers for k+1 (indices already resident -> no wait at issue)
        if (more) {
#pragma unroll
            for (int p = 0; p < NPASS; ++p)
                ag[p] = *(const s16x8*)(xin + (long long)nidx[p] * CK + schunk * 8);
            // 3. indices for k+2 (land during this stage, cheap L1/L2)
#pragma unroll
            for (int p = 0; p < NPASS; ++p) {
                int row = n0 + p * RPP + srow;
                nidx[p] = (row < NSITES && k + 2 < nk) ? nbr[row * KOFFS + k + 2] : NSITES;
            }
        }

        // 4. MFMA phase on current buffer (waits only on B + LDS)
#pragma unroll
        for (int ks = 0; ks < KSTEPS; ++ks) {
            s16x8 af[4];
#pragma unroll
            for (int rt = 0; rt < 4; ++rt) {
                int r = rt * 16 + m;
                af[rt] = *(const s16x8*)(abuf + r * CK + (((ks * 4 + q) ^ (r & SWZ)) * 8));
            }
#pragma unroll
            for (int rt = 0; rt < 4; ++rt)
#pragma unroll
                for (int ct = 0; ct < 2; ++ct)
                    acc[rt][ct] = __builtin_amdgcn_mfma_f32_16x16x32_bf16(
                        af[rt], bf[ct][ks], acc[rt][ct], 0, 0, 0);
        }

        // 5. stage k+1 (gather drain lands here, after the MFMA window)
        if (more) {
#pragma unroll
            for (int p = 0; p < NPASS; ++p) {
                int r = p * RPP + srow;
                *(s16x8*)(wbuf + r * CK + ((schunk ^ (r & SWZ)) * 8)) = ag[p];
            }
        }
        __syncthreads();
    }

    // Store y (bf16): C/D layout col=lane&15, row=(lane>>4)*4+reg  [m89-verified]
#pragma unroll
    for (int rt = 0; rt < 4; ++rt) {
        int rowb = n0 + rt * 16 + q * 4;
#pragma unroll
        for (int ct = 0; ct < 2; ++ct) {
            int col = wc + ct * 16 + m;
#pragma unroll
            for (int r = 0; r < 4; ++r) {
                int row = rowb + r;
                if (row < NSITES) yout[(long long)row * COUT + col] = f2bf(acc[rt][ct][r]);
            }
        }
    }

    if (STATS) {
#pragma unroll
        for (int ct = 0; ct < 2; ++ct) {
            float s = 0.f, ss = 0.f;
#pragma unroll
            for (int rt = 0; rt < 4; ++rt)
#pragma unroll
                for (int r = 0; r < 4; ++r) {
                    float v = acc[rt][ct][r];
                    s += v; ss += v * v;
                }
            s += __shfl_xor(s, 16); ss += __shfl_xor(ss, 16);
            s += __shfl_xor(s, 32); ss += __shfl_xor(ss, 32);
            if (q == 0) {
                int col = wc + ct * 16 + m;
                int slot = blockIdx.x & 63;  // 64-slot tree cuts atomic contention
                atomicAdd(psum + slot * COUT + col, s);
                atomicAdd(psq + slot * COUT + col, ss);
            }
        }
    }

    if (IDENT_FUSE) {
        // identity = x @ W_skip for the same 64 rows (no gather); reuses acc regs
#pragma unroll
        for (int rt = 0; rt < 4; ++rt)
#pragma unroll
            for (int ct = 0; ct < 2; ++ct)
#pragma unroll
                for (int r = 0; r < 4; ++r) acc[rt][ct][r] = 0.0f;
        s16x8 aid[NPASS];
#pragma unroll
        for (int p = 0; p < NPASS; ++p) {
            int row = n0 + p * RPP + srow;
            long long idx = (row < NSITES) ? row : NSITES;
            aid[p] = *(const s16x8*)(xin + idx * CK + schunk * 8);
        }
        s16x8 bfi[2][KSTEPS];
#pragma unroll
        for (int ct = 0; ct < 2; ++ct)
#pragma unroll
            for (int ks = 0; ks < KSTEPS; ++ks)
                bfi[ct][ks] = *(const s16x8*)(Wskt + (wc + ct * 16 + m) * CK + ks * 32 + q * 8);
        // loop-end barrier guarantees a_tile[0] reads are complete
#pragma unroll
        for (int p = 0; p < NPASS; ++p) {
            int r = p * RPP + srow;
            *(s16x8*)(a_tile[0] + r * CK + ((schunk ^ (r & SWZ)) * 8)) = aid[p];
        }
        __syncthreads();
#pragma unroll
        for (int ks = 0; ks < KSTEPS; ++ks) {
            s16x8 af[4];
#pragma unroll
            for (int rt = 0; rt < 4; ++rt) {
                int r = rt * 16 + m;
                af[rt] = *(const s16x8*)(a_tile[0] + r * CK + (((ks * 4 + q) ^ (r & SWZ)) * 8));
            }
#pragma unroll
            for (int rt = 0; rt < 4; ++rt)
#pragma unroll
                for (int ct = 0; ct < 2; ++ct)
                    acc[rt][ct] = __builtin_amdgcn_mfma_f32_16x16x32_bf16(
                        af[rt], bfi[ct][ks], acc[rt][ct], 0, 0, 0);
        }
#pragma unroll
        for (int rt = 0; rt < 4; ++rt) {
            int rowb = n0 + rt * 16 + q * 4;
#pragma unroll
            for (int ct = 0; ct < 2; ++ct) {
                int col = wc + ct * 16 + m;
#pragma unroll
                for (int r = 0; r < 4; ++r) {
                    int row = rowb + r;
                    if (row < NSITES) outid[(long long)row * COUT + col] = acc[rt][ct][r];
                }
            }
        }
    }
}

// ---------- reduce 64 slots -> per-column affine (a = gamma*rsqrt(var+eps), b = beta - mu*a) ----------
__global__ void bn_stats_kernel(const float* __restrict__ psum, const float* __restrict__ psq,
                                const float* __restrict__ gamma, const float* __restrict__ beta,
                                float* __restrict__ ab) {
    int col = threadIdx.x;  // 128 threads
    float s = 0.f, ss = 0.f;
    for (int i = 0; i < 64; ++i) { s += psum[i * COUT + col]; ss += psq[i * COUT + col]; }
    const float inv_n = 1.0f / (float)NSITES;
    float mu = s * inv_n;
    float var = ss * inv_n - mu * mu;
    float rs = rsqrtf(var + 1e-5f);
    float a = gamma[col] * rs;
    ab[col] = a;
    ab[COUT + col] = beta[col] - mu * a;
}

// ---------- h = bf16(relu(y*a+b)), plus zero sentinel row; y is bf16 ----------
__global__ void bn_apply_kernel(const u16* __restrict__ y, const float* __restrict__ ab,
                                u16* __restrict__ h) {
    long long e = ((long long)blockIdx.x * 256 + threadIdx.x) * 8;
    if (e >= (long long)(NSITES + 1) * COUT) return;
    s16x8 o;
    if (e < (long long)NSITES * COUT) {
        int cb = (int)(e & (COUT - 1));
        s16x8 v = *(const s16x8*)(y + e);
#pragma unroll
        for (int j = 0; j < 8; ++j) {
            float r = bf2f((u16)v[j]) * ab[cb + j] + ab[COUT + cb + j];
            o[j] = (short)f2bf(fmaxf(r, 0.f));
        }
    } else {
#pragma unroll
        for (int j = 0; j < 8; ++j) o[j] = 0;
    }
    *(s16x8*)(h + e) = o;
}

// ---------- out = relu(y*a+b) + identity (identity resident in d_out); y is bf16 ----------
__global__ void final_kernel(const u16* __restrict__ y, const float* __restrict__ ab,
                             float* __restrict__ out) {
    long long e = ((long long)blockIdx.x * 256 + threadIdx.x) * 8;
    if (e >= (long long)NSITES * COUT) return;
    int cb = (int)(e & (COUT - 1));
    s16x8 v = *(const s16x8*)(y + e);
    float4 i0 = *(const float4*)(out + e);
    float4 i1 = *(const float4*)(out + e + 4);
    float is[8] = {i0.x, i0.y, i0.z, i0.w, i1.x, i1.y, i1.z, i1.w};
    float os[8];
#pragma unroll
    for (int j = 0; j < 8; ++j) {
        float r = bf2f((u16)v[j]) * ab[cb + j] + ab[COUT + cb + j];
        os[j] = fmaxf(r, 0.f) + is[j];
    }
    *(float4*)(out + e) = make_float4(os[0], os[1], os[2], os[3]);
    *(float4*)(out + e + 4) = make_float4(os[4], os[5], os[6], os[7]);
}

extern "C" void kernel_launch(void* const* d_in, const int* in_sizes, int n_in,
                              void* d_out, int out_size, void* d_ws, size_t ws_size,
                              hipStream_t stream) {
    const float* x   = (const float*)d_in[0];
    const int*   nbr = (const int*)d_in[1];
    const float* W1  = (const float*)d_in[2];
    const float* g1  = (const float*)d_in[3];
    const float* b1  = (const float*)d_in[4];
    const float* W2  = (const float*)d_in[5];
    const float* g2  = (const float*)d_in[6];
    const float* b2  = (const float*)d_in[7];
    const float* Wsk = (const float*)d_in[8];
    float* out = (float*)d_out;

    // workspace layout (bytes, 16B-aligned); total ~66 MB
    char* ws = (char*)d_ws;
    u16*   xb   = (u16*)(ws);                    // (N+1)*64 bf16      = 12,800,128 B
    u16*   W1t  = (u16*)(ws + 12800128);         // 27*128*64 bf16     =    442,368 B
    u16*   W2t  = (u16*)(ws + 13242496);         // 27*128*128 bf16    =    884,736 B
    u16*   Wskt = (u16*)(ws + 14127232);         // 128*64 bf16        =     16,384 B
    u16*   y    = (u16*)(ws + 14143616);         // N*128 bf16         = 25,600,000 B
    u16*   h1   = (u16*)(ws + 39743616);         // (N+1)*128 bf16     = 25,600,256 B
    float* ps1  = (float*)(ws + 65343872);       // 4 * 64*128 f32 partials
    float* pq1  = ps1 + 8192;
    float* ps2  = pq1 + 8192;
    float* pq2  = ps2 + 8192;
    float* ab1  = pq2 + 8192;                    // 2*2*128 f32 affine params
    float* ab2  = ab1 + 256;

    const int NBLK = (NSITES + 63) / 64;  // 1563

    prep_kernel<<<2752, 256, 0, stream>>>(W1, W2, Wsk, W1t, W2t, Wskt, ps1);
    convert_x_kernel<<<3126, 256, 0, stream>>>(x, xb);
    // conv1 + fused stats + fused identity (identity -> d_out)
    conv_kernel<64, true, true><<<NBLK, 256, 0, stream>>>(xb, nbr, W1t, y, ps1, pq1, KOFFS, Wskt, out);
    bn_stats_kernel<<<1, 128, 0, stream>>>(ps1, pq1, g1, b1, ab1);
    bn_apply_kernel<<<6251, 256, 0, stream>>>(y, ab1, h1);
    // conv2 + fused stats (reuses y buffer)
    conv_kernel<128, false, true><<<NBLK, 256, 0, stream>>>(h1, nbr, W2t, y, ps2, pq2, KOFFS, nullptr, nullptr);
    bn_stats_kernel<<<1, 128, 0, stream>>>(ps2, pq2, g2, b2, ab2);
    final_kernel<<<6250, 256, 0, stream>>>(y, ab2, out);
}